// Round 12
// baseline (359.659 us; speedup 1.0000x reference)
//
#include <hip/hip_runtime.h>
#include <math.h>
#include <stdint.h>

#define NI 100000   // N_ITEMS
#define NB 512      // batch
#define NH 256      // hidden H
#define H3 768      // 3*H
#define NT 1563     // ceil(NI/64) n-tiles
#define GRID_OUT 512

typedef _Float16 f16x8 __attribute__((ext_vector_type(8)));
typedef _Float16 f16x4 __attribute__((ext_vector_type(4)));
typedef float    f32x4 __attribute__((ext_vector_type(4)));

__device__ __forceinline__ float tanh_fast(float x) {
    x = fminf(fmaxf(x, -9.0f), 9.0f);
    const float e = __expf(2.0f * x);
    return (e - 1.0f) * __builtin_amdgcn_rcpf(e + 1.0f);
}

// ---------------- GRU gate elementwise (layer 0: gather x_proj inline) ----------------
__global__ void k_gates0(const int* __restrict__ idx,
                         const float* __restrict__ Wih0,   // (768, NI)
                         const float* __restrict__ bih0,   // (768)
                         const float* __restrict__ hp,     // (512,768)
                         const float* __restrict__ hprev,  // (512,256)
                         float* __restrict__ hnew)         // (512,256)
{
    const int b = blockIdx.x;
    const int j = threadIdx.x;          // 0..255
    const int ib = idx[b];
    const float xr = Wih0[(size_t)(j          ) * NI + ib] + bih0[j];
    const float xz = Wih0[(size_t)(j + NH     ) * NI + ib] + bih0[j + NH];
    const float xn = Wih0[(size_t)(j + 2 * NH ) * NI + ib] + bih0[j + 2 * NH];
    const float hr = hp[b * H3 + j];
    const float hz = hp[b * H3 + NH + j];
    const float hn = hp[b * H3 + 2 * NH + j];
    const float h  = hprev[b * NH + j];
    const float r = 1.0f / (1.0f + expf(-(xr + hr)));
    const float z = 1.0f / (1.0f + expf(-(xz + hz)));
    const float n = tanhf(xn + r * hn);
    hnew[b * NH + j] = (1.0f - z) * n + z * h;
}

// ---------------- GRU gate elementwise (layer 1) ----------------
__global__ void k_gates(const float* __restrict__ xp,
                        const float* __restrict__ hp,
                        const float* __restrict__ hprev,
                        float* __restrict__ hnew)
{
    const int b = blockIdx.x;
    const int j = threadIdx.x;
    const float xr = xp[b * H3 + j];
    const float xz = xp[b * H3 + NH + j];
    const float xn = xp[b * H3 + 2 * NH + j];
    const float hr = hp[b * H3 + j];
    const float hz = hp[b * H3 + NH + j];
    const float hn = hp[b * H3 + 2 * NH + j];
    const float h  = hprev[b * NH + j];
    const float r = 1.0f / (1.0f + expf(-(xr + hr)));
    const float z = 1.0f / (1.0f + expf(-(xz + hz)));
    const float n = tanhf(xn + r * hn);
    hnew[b * NH + j] = (1.0f - z) * n + z * h;
}

// ---------------- layer 2 gates: also emit fp16 copy of h2 for the MFMA GEMM --------
__global__ void k_gates_last(const float* __restrict__ xp,
                             const float* __restrict__ hp,
                             const float* __restrict__ hprev,
                             float* __restrict__ hnew,
                             _Float16* __restrict__ Xh)    // (512,256) fp16
{
    const int b = blockIdx.x;
    const int j = threadIdx.x;
    const float xr = xp[b * H3 + j];
    const float xz = xp[b * H3 + NH + j];
    const float xn = xp[b * H3 + 2 * NH + j];
    const float hr = hp[b * H3 + j];
    const float hz = hp[b * H3 + NH + j];
    const float hn = hp[b * H3 + 2 * NH + j];
    const float h  = hprev[b * NH + j];
    const float r = 1.0f / (1.0f + expf(-(xr + hr)));
    const float z = 1.0f / (1.0f + expf(-(xz + hz)));
    const float n = tanhf(xn + r * hn);
    const float v = (1.0f - z) * n + z * h;
    hnew[b * NH + j] = v;
    Xh[b * NH + j] = (_Float16)v;
}

// ---------------- small tiled fp32 GEMM:  C = A @ B.T + bias (z-batched) ----------------
__global__ __launch_bounds__(256)
void k_gemm_small(const float* __restrict__ A0,
                  const float* __restrict__ B0,
                  const float* __restrict__ bias0,
                  float* __restrict__ C0,
                  int M, int N, int K,
                  int sA, int sB, int sBias, int sC)
{
    constexpr int BM = 64, BN = 64, BK = 32;
    __shared__ float As[BK][BM];
    __shared__ float Bs[BK][BN];

    const float* A    = A0 + (size_t)blockIdx.z * sA;
    const float* Bm   = B0 + (size_t)blockIdx.z * sB;
    const float* bias = bias0 + (size_t)blockIdx.z * sBias;
    float*       C    = C0 + (size_t)blockIdx.z * sC;

    const int tid = threadIdx.x;
    const int tx  = tid & 15;
    const int ty  = tid >> 4;
    const int m0  = blockIdx.x * BM;
    const int n0  = blockIdx.y * BN;

    float acc[4][4];
#pragma unroll
    for (int i = 0; i < 4; i++)
#pragma unroll
        for (int j = 0; j < 4; j++) acc[i][j] = 0.0f;

    for (int k0 = 0; k0 < K; k0 += BK) {
#pragma unroll
        for (int f = 0; f < 2; f++) {
            const int fid = tid + f * 256;
            const int row = fid >> 3;
            const int t4  = fid & 7;
            const int mp  = row ^ ((t4 & 3) << 3);
            {
                const float4 v = *(const float4*)(A + (size_t)(m0 + row) * K + k0 + t4 * 4);
                As[t4 * 4 + 0][mp] = v.x; As[t4 * 4 + 1][mp] = v.y;
                As[t4 * 4 + 2][mp] = v.z; As[t4 * 4 + 3][mp] = v.w;
            }
            {
                const float4 v = *(const float4*)(Bm + (size_t)(n0 + row) * K + k0 + t4 * 4);
                Bs[t4 * 4 + 0][mp] = v.x; Bs[t4 * 4 + 1][mp] = v.y;
                Bs[t4 * 4 + 2][mp] = v.z; Bs[t4 * 4 + 3][mp] = v.w;
            }
        }
        __syncthreads();
#pragma unroll
        for (int kk = 0; kk < BK; kk++) {
            const int s = ((kk >> 2) & 3) << 3;
            const float4 a0 = *(const float4*)&As[kk][(ty * 4) ^ s];
            const float4 b0 = *(const float4*)&Bs[kk][(tx * 4) ^ s];
            const float av[4] = {a0.x, a0.y, a0.z, a0.w};
            const float bv[4] = {b0.x, b0.y, b0.z, b0.w};
#pragma unroll
            for (int i = 0; i < 4; i++)
#pragma unroll
                for (int j = 0; j < 4; j++)
                    acc[i][j] = fmaf(av[i], bv[j], acc[i][j]);
        }
        __syncthreads();
    }

#pragma unroll
    for (int i = 0; i < 4; i++) {
        const size_t rowoff = (size_t)(m0 + ty * 4 + i) * N;
        const int gn = n0 + tx * 4;
        const float4 bb = *(const float4*)(bias + gn);
        float4 v;
        v.x = acc[i][0] + bb.x; v.y = acc[i][1] + bb.y;
        v.z = acc[i][2] + bb.z; v.w = acc[i][3] + bb.w;
        *(float4*)(C + rowoff + gn) = v;
    }
}

// ---------------- output projection: act = tanh(x @ Wout.T + bout), fp16 MFMA ----------
// R12 = R11 pipeline + the missing barrier. Multi-tile pipelined block, 2 blocks/CU,
// TWO barriers per tile:
//   issueA -> K(0..3) -> writeA(dead buf) -> issueB -> K(4..7)
//   -> __syncthreads   [ALL waves done reading Wbuf[cur] -- R11's missing sync; every
//                       wave reads the WHOLE panel, so epilogue overwrite raced]
//   -> epilogue through private 4KB quarter of Wbuf[cur] (intra-wave lgkmcnt order)
//   -> writeB(dead buf) -> __syncthreads -> flip.
// launch_bounds(512,4): 8-wave block = 128-reg cap; stg split into 32-row chunks
// (16 regs) so no spill (R10 canary: FETCH=108MB). Swizzles/math verified r8-r10.
// mfma(A=W, B=X): D row((lane>>4)*4+reg)=n, col(lane&15)=m.
__global__ __launch_bounds__(512, 4)
void k_out_mfma(const _Float16* __restrict__ Xh,  // (512,256) fp16
                const float* __restrict__ W,      // (NI,256) fp32
                const float* __restrict__ bout,   // (NI)
                float* __restrict__ C)            // (512,NI)
{
    __shared__ __align__(16) _Float16 Wbuf[2][64 * 256];   // 2 x 32 KB

    const int tid  = threadIdx.x;
    const int w    = tid >> 6;                 // wave 0..7 -> m rows [w*64, w*64+64)
    const int lane = tid & 63;
    const int lr   = lane & 15;
    const int lg   = lane >> 4;                // 0..3

    const _Float16* xbase = Xh + (size_t)(w * 64 + lr) * NH + lg * 8;

    float4 stg[4];                             // one 32-row chunk in flight

    // ---- issue global W reads for chunk ch (rows ch*32..+32) of tile ny ----
    auto issue_chunk = [&](int ny, int ch) {
        const int base = ny * 64 + ch * 32;
#pragma unroll
        for (int j = 0; j < 4; ++j) {
            const int fid = j * 512 + tid;     // 0..2047
            const int row = fid >> 6;          // 0..31
            const int c   = fid & 63;
            int gr = base + row; if (gr >= NI) gr = NI - 1;
            stg[j] = *(const float4*)(W + (size_t)gr * NH + c * 4);
        }
    };
    // ---- cvt + swizzled ds_write of staged chunk into buf ----
    auto write_chunk = [&](_Float16* buf, int ch) {
#pragma unroll
        for (int j = 0; j < 4; ++j) {
            const int fid = j * 512 + tid;
            const int row = ch * 32 + (fid >> 6);        // panel row 0..63
            const int c   = fid & 63;
            const int s   = c >> 1;                      // 16B fp16 slot 0..31
            const int ps  = (s & 24) | ((s ^ row) & 7);  // XOR swizzle
            f16x4 h;
            h[0] = (_Float16)stg[j].x; h[1] = (_Float16)stg[j].y;
            h[2] = (_Float16)stg[j].z; h[3] = (_Float16)stg[j].w;
            *(f16x4*)((char*)buf + row * 512 + ps * 16 + (c & 1) * 8) = h;
        }
    };
    // ---- half K-loop (tt = t0..t0+4) on buf ----
    auto khalf = [&](const _Float16* buf, f32x4 (&acc)[4][4], int t0) {
#pragma unroll
        for (int tt = t0; tt < t0 + 4; ++tt) {
            f16x8 xf[4];
#pragma unroll
            for (int mf = 0; mf < 4; ++mf)
                xf[mf] = *(const f16x8*)(xbase + mf * 16 * NH + tt * 32);
#pragma unroll
            for (int nf = 0; nf < 4; ++nf) {
                const int rl = nf * 16 + lr;             // W-panel row 0..63
                const int s  = tt * 4 + lg;              // 16B slot 0..31
                const int ps = (s & 24) | ((s ^ rl) & 7);
                const f16x8 wf = *(const f16x8*)((const char*)buf + rl * 512 + ps * 16);
#pragma unroll
                for (int mf = 0; mf < 4; ++mf)
                    acc[nf][mf] = __builtin_amdgcn_mfma_f32_16x16x32_f16(
                        wf, xf[mf], acc[nf][mf], 0, 0, 0);
            }
        }
    };

    // ---- prologue: stage first tile fully ----
    issue_chunk(blockIdx.x, 0);
    write_chunk(Wbuf[0], 0);
    issue_chunk(blockIdx.x, 1);
    write_chunk(Wbuf[0], 1);
    __syncthreads();
    int cur = 0;

    for (int t = blockIdx.x; t < NT; t += GRID_OUT) {
        const int n0 = t * 64;
        const bool has_next = (t + GRID_OUT) < NT;

        f32x4 acc[4][4];
#pragma unroll
        for (int nf = 0; nf < 4; ++nf)
#pragma unroll
            for (int mf = 0; mf < 4; ++mf) acc[nf][mf] = (f32x4){0.f, 0.f, 0.f, 0.f};

        if (has_next) issue_chunk(t + GRID_OUT, 0);      // A reads fly under K(0..3)
        khalf(Wbuf[cur], acc, 0);
        if (has_next) {
            write_chunk(Wbuf[cur ^ 1], 0);               // dead buffer: safe mid-tile
            issue_chunk(t + GRID_OUT, 1);                // B reads fly under K(4..7)
        }
        khalf(Wbuf[cur], acc, 4);

        __syncthreads();   // ALL waves done reading Wbuf[cur] (R11's missing barrier)

        // ---- epilogue through private 4KB quarter of freed Wbuf[cur] ----
        float* area = (float*)Wbuf[cur] + w * 1024;      // 16 rows x 64 floats
#pragma unroll
        for (int mf = 0; mf < 4; ++mf) {
            // write 16 rows (m = w*64+mf*16+lr), bias+tanh applied here
#pragma unroll
            for (int nf = 0; nf < 4; ++nf) {
                const int q  = nf * 4 + lg;              // float4 slot 0..15
                const int gn = n0 + q * 4;
                const float4 bb = (gn < NI) ? *(const float4*)(bout + gn)
                                            : make_float4(0.f, 0.f, 0.f, 0.f);
                const int pq = q ^ lr;                   // bijective per row
                float4 v;
                v.x = tanh_fast(acc[nf][mf][0] + bb.x);
                v.y = tanh_fast(acc[nf][mf][1] + bb.y);
                v.z = tanh_fast(acc[nf][mf][2] + bb.z);
                v.w = tanh_fast(acc[nf][mf][3] + bb.w);
                *(float4*)(area + lr * 64 + pq * 4) = v;
            }
            // read rows out + 256B-contiguous stores (4 rows x 256B per instr)
#pragma unroll
            for (int k = 0; k < 4; ++k) {
                const int r  = 4 * k + (lane >> 4);      // 0..15
                const int q  = lane & 15;
                const int pq = q ^ r;
                const int gn = n0 + q * 4;
                const f32x4 v = *(const f32x4*)(area + r * 64 + pq * 4);
                if (gn < NI)
                    *(f32x4*)(C + (size_t)(w * 64 + mf * 16 + r) * NI + gn) = v;
            }
        }

        if (has_next) write_chunk(Wbuf[cur ^ 1], 1);
        __syncthreads();                         // epilogue reads + writeB drained
        cur ^= 1;
    }
}

extern "C" void kernel_launch(void* const* d_in, const int* in_sizes, int n_in,
                              void* d_out, int out_size, void* d_ws, size_t ws_size,
                              hipStream_t stream)
{
    const int*   idx    = (const int*)  d_in[0];
    const float* hidden = (const float*)d_in[1];   // (3,512,256)
    const float* Wih0   = (const float*)d_in[2];   // (768,100000)
    const float* WihHi  = (const float*)d_in[3];   // (2,768,256)
    const float* Whh    = (const float*)d_in[4];   // (3,768,256)
    const float* bih    = (const float*)d_in[5];   // (3,768)
    const float* bhh    = (const float*)d_in[6];   // (3,768)
    const float* Wout   = (const float*)d_in[7];   // (100000,256)
    const float* bout   = (const float*)d_in[8];   // (100000)

    float* act  = (float*)d_out;                  // (512, NI)
    float* hnew = act + (size_t)NB * NI;          // (3,512,256)
    // fp32 scratch lives in the activation region; final GEMM overwrites it.
    float* hp = act;                              // (3,512,768)
    float* xp = act + 3 * NB * H3;                // (512,768)
    // fp16 X lives in d_ws (must survive while the big GEMM writes act)
    _Float16* Xh = (_Float16*)d_ws;               // (512,256) = 256 KB

    const dim3 bs(256);
    const dim3 gs_hp(NB / 64, H3 / 64, 3);
    const dim3 gs_xp(NB / 64, H3 / 64, 1);

    // ---- all hidden-projections (depend only on input `hidden`) ----
    k_gemm_small<<<gs_hp, bs, 0, stream>>>(hidden, Whh, bhh, hp,
                                           NB, H3, NH, NB * NH, H3 * NH, H3, NB * H3);
    // ---- layer 0 (x_proj gathered inline) ----
    k_gates0<<<NB, bs, 0, stream>>>(idx, Wih0, bih, hp, hidden, hnew);
    // ---- layer 1 ----
    k_gemm_small<<<gs_xp, bs, 0, stream>>>(hnew, WihHi, bih + H3, xp,
                                           NB, H3, NH, 0, 0, 0, 0);
    k_gates<<<NB, bs, 0, stream>>>(xp, hp + NB * H3, hidden + NB * NH, hnew + NB * NH);
    // ---- layer 2 (also emits fp16 h2) ----
    k_gemm_small<<<gs_xp, bs, 0, stream>>>(hnew + NB * NH, WihHi + H3 * NH, bih + 2 * H3, xp,
                                           NB, H3, NH, 0, 0, 0, 0);
    k_gates_last<<<NB, bs, 0, stream>>>(xp, hp + 2 * NB * H3, hidden + 2 * NB * NH,
                                        hnew + 2 * NB * NH, Xh);

    // ---- output projection: 512 pipelined blocks, 2/CU, ~3 tiles each ----
    k_out_mfma<<<dim3(GRID_OUT), dim3(512), 0, stream>>>(Xh, Wout, bout, act);
}

// Round 13
// 221.607 us; speedup vs baseline: 1.6230x; 1.6230x over previous
//
#include <hip/hip_runtime.h>
#include <math.h>
#include <stdint.h>

#define NI 100000   // N_ITEMS
#define NB 512      // batch
#define NH 256      // hidden H
#define H3 768      // 3*H
#define NT 1563     // ceil(NI/64) n-tiles
#define GRID_OUT 256

typedef _Float16 f16x8 __attribute__((ext_vector_type(8)));
typedef float    f32x4 __attribute__((ext_vector_type(4)));

__device__ __forceinline__ float tanh_fast(float x) {
    x = fminf(fmaxf(x, -9.0f), 9.0f);
    const float e = __expf(2.0f * x);
    return (e - 1.0f) * __builtin_amdgcn_rcpf(e + 1.0f);
}

// ---------------- GRU gate elementwise (layer 0: gather x_proj inline) ----------------
__global__ void k_gates0(const int* __restrict__ idx,
                         const float* __restrict__ Wih0,   // (768, NI)
                         const float* __restrict__ bih0,   // (768)
                         const float* __restrict__ hp,     // (512,768)
                         const float* __restrict__ hprev,  // (512,256)
                         float* __restrict__ hnew)         // (512,256)
{
    const int b = blockIdx.x;
    const int j = threadIdx.x;          // 0..255
    const int ib = idx[b];
    const float xr = Wih0[(size_t)(j          ) * NI + ib] + bih0[j];
    const float xz = Wih0[(size_t)(j + NH     ) * NI + ib] + bih0[j + NH];
    const float xn = Wih0[(size_t)(j + 2 * NH ) * NI + ib] + bih0[j + 2 * NH];
    const float hr = hp[b * H3 + j];
    const float hz = hp[b * H3 + NH + j];
    const float hn = hp[b * H3 + 2 * NH + j];
    const float h  = hprev[b * NH + j];
    const float r = 1.0f / (1.0f + expf(-(xr + hr)));
    const float z = 1.0f / (1.0f + expf(-(xz + hz)));
    const float n = tanhf(xn + r * hn);
    hnew[b * NH + j] = (1.0f - z) * n + z * h;
}

// ---------------- GRU gate elementwise (layer 1) ----------------
__global__ void k_gates(const float* __restrict__ xp,
                        const float* __restrict__ hp,
                        const float* __restrict__ hprev,
                        float* __restrict__ hnew)
{
    const int b = blockIdx.x;
    const int j = threadIdx.x;
    const float xr = xp[b * H3 + j];
    const float xz = xp[b * H3 + NH + j];
    const float xn = xp[b * H3 + 2 * NH + j];
    const float hr = hp[b * H3 + j];
    const float hz = hp[b * H3 + NH + j];
    const float hn = hp[b * H3 + 2 * NH + j];
    const float h  = hprev[b * NH + j];
    const float r = 1.0f / (1.0f + expf(-(xr + hr)));
    const float z = 1.0f / (1.0f + expf(-(xz + hz)));
    const float n = tanhf(xn + r * hn);
    hnew[b * NH + j] = (1.0f - z) * n + z * h;
}

// ---------------- layer 2 gates: also emit fp16 copy of h2 for the MFMA GEMM --------
__global__ void k_gates_last(const float* __restrict__ xp,
                             const float* __restrict__ hp,
                             const float* __restrict__ hprev,
                             float* __restrict__ hnew,
                             _Float16* __restrict__ Xh)    // (512,256) fp16
{
    const int b = blockIdx.x;
    const int j = threadIdx.x;
    const float xr = xp[b * H3 + j];
    const float xz = xp[b * H3 + NH + j];
    const float xn = xp[b * H3 + 2 * NH + j];
    const float hr = hp[b * H3 + j];
    const float hz = hp[b * H3 + NH + j];
    const float hn = hp[b * H3 + 2 * NH + j];
    const float h  = hprev[b * NH + j];
    const float r = 1.0f / (1.0f + expf(-(xr + hr)));
    const float z = 1.0f / (1.0f + expf(-(xz + hz)));
    const float n = tanhf(xn + r * hn);
    const float v = (1.0f - z) * n + z * h;
    hnew[b * NH + j] = v;
    Xh[b * NH + j] = (_Float16)v;
}

// ---------------- small tiled fp32 GEMM:  C = A @ B.T + bias (z-batched) ----------------
__global__ __launch_bounds__(256)
void k_gemm_small(const float* __restrict__ A0,
                  const float* __restrict__ B0,
                  const float* __restrict__ bias0,
                  float* __restrict__ C0,
                  int M, int N, int K,
                  int sA, int sB, int sBias, int sC)
{
    constexpr int BM = 64, BN = 64, BK = 32;
    __shared__ float As[BK][BM];
    __shared__ float Bs[BK][BN];

    const float* A    = A0 + (size_t)blockIdx.z * sA;
    const float* Bm   = B0 + (size_t)blockIdx.z * sB;
    const float* bias = bias0 + (size_t)blockIdx.z * sBias;
    float*       C    = C0 + (size_t)blockIdx.z * sC;

    const int tid = threadIdx.x;
    const int tx  = tid & 15;
    const int ty  = tid >> 4;
    const int m0  = blockIdx.x * BM;
    const int n0  = blockIdx.y * BN;

    float acc[4][4];
#pragma unroll
    for (int i = 0; i < 4; i++)
#pragma unroll
        for (int j = 0; j < 4; j++) acc[i][j] = 0.0f;

    for (int k0 = 0; k0 < K; k0 += BK) {
#pragma unroll
        for (int f = 0; f < 2; f++) {
            const int fid = tid + f * 256;
            const int row = fid >> 3;
            const int t4  = fid & 7;
            const int mp  = row ^ ((t4 & 3) << 3);
            {
                const float4 v = *(const float4*)(A + (size_t)(m0 + row) * K + k0 + t4 * 4);
                As[t4 * 4 + 0][mp] = v.x; As[t4 * 4 + 1][mp] = v.y;
                As[t4 * 4 + 2][mp] = v.z; As[t4 * 4 + 3][mp] = v.w;
            }
            {
                const float4 v = *(const float4*)(Bm + (size_t)(n0 + row) * K + k0 + t4 * 4);
                Bs[t4 * 4 + 0][mp] = v.x; Bs[t4 * 4 + 1][mp] = v.y;
                Bs[t4 * 4 + 2][mp] = v.z; Bs[t4 * 4 + 3][mp] = v.w;
            }
        }
        __syncthreads();
#pragma unroll
        for (int kk = 0; kk < BK; kk++) {
            const int s = ((kk >> 2) & 3) << 3;
            const float4 a0 = *(const float4*)&As[kk][(ty * 4) ^ s];
            const float4 b0 = *(const float4*)&Bs[kk][(tx * 4) ^ s];
            const float av[4] = {a0.x, a0.y, a0.z, a0.w};
            const float bv[4] = {b0.x, b0.y, b0.z, b0.w};
#pragma unroll
            for (int i = 0; i < 4; i++)
#pragma unroll
                for (int j = 0; j < 4; j++)
                    acc[i][j] = fmaf(av[i], bv[j], acc[i][j]);
        }
        __syncthreads();
    }

#pragma unroll
    for (int i = 0; i < 4; i++) {
        const size_t rowoff = (size_t)(m0 + ty * 4 + i) * N;
        const int gn = n0 + tx * 4;
        const float4 bb = *(const float4*)(bias + gn);
        float4 v;
        v.x = acc[i][0] + bb.x; v.y = acc[i][1] + bb.y;
        v.z = acc[i][2] + bb.z; v.w = acc[i][3] + bb.w;
        *(float4*)(C + rowoff + gn) = v;
    }
}

// ---------------- output projection: act = tanh(x @ Wout.T + bout), fp16 MFMA ----------
// R13: R10's clean register config + zero-VGPR staging. Grid 256 (1 block/CU), each
// block walks ~6 n-tiles with double-buffered 2x64KB fp32 W panels (128 KB LDS).
// Per tile:  issue global_load_lds(tile t+1 -> buf^1)   [zero VGPR, in flight under K]
//            K-loop on buf: 8t x {4 X-loads(L1), 8 swizzled ds_read_b128+cvt, 16 MFMA}
//            __syncthreads  [K reads done; t+1 loads drained -- they had the K-loop]
//            2-pass C transpose through freed buf (R7-verified), 256B-contig stores
// launch_bounds(512,2): empirical allocator law (R9/R10/R12): cap ~256/minWaves ->
// (512,2)=256-reg cap, clean at 128 (R10 canary FETCH=108MB); minWaves>=3 spills.
// Swizzle (R7-verified): 16B chunk p of row r stored at linear fid, fetched from
// global chunk p^(r&7); K-read undoes it. mfma(A=W, B=X): D row((lane>>4)*4+reg)=n,
// col(lane&15)=m (verified r1-r12).
__global__ __launch_bounds__(512, 2)
void k_out_mfma(const _Float16* __restrict__ Xh,  // (512,256) fp16
                const float* __restrict__ W,      // (NI,256) fp32
                const float* __restrict__ bout,   // (NI)
                float* __restrict__ C)            // (512,NI)
{
    __shared__ __align__(16) float Wbuf[2][64 * 256];   // 2 x 64 KB fp32

    const int tid  = threadIdx.x;
    const int w    = tid >> 6;                 // wave 0..7 -> m rows [w*64, w*64+64)
    const int lane = tid & 63;
    const int lr   = lane & 15;
    const int lg   = lane >> 4;                // 0..3

    const _Float16* xbase = Xh + (size_t)(w * 64 + lr) * NH + lg * 8;

    // ---- stage a 64-row W panel via global_load_lds (no registers consumed) ----
    auto stage = [&](float* buf, int ny) {
#pragma unroll
        for (int it = 0; it < 8; ++it) {
            const int fid = it * 512 + tid;        // 16B chunk id 0..4095
            const int row = fid >> 6;              // 0..63
            const int p   = fid & 63;              // physical chunk in LDS row
            int gr = ny * 64 + row; if (gr >= NI) gr = NI - 1;   // cols masked at store
            const float* src = W + (size_t)gr * NH + (size_t)(p ^ (row & 7)) * 4;
            __builtin_amdgcn_global_load_lds(
                (const __attribute__((address_space(1))) void*)src,
                (__attribute__((address_space(3))) void*)(buf + fid * 4),
                16, 0, 0);
        }
    };

    // ---- prologue ----
    stage(Wbuf[0], blockIdx.x);
    __syncthreads();
    int cur = 0;

    for (int t = blockIdx.x; t < NT; t += GRID_OUT) {
        const int n0 = t * 64;
        if (t + GRID_OUT < NT) stage(Wbuf[cur ^ 1], t + GRID_OUT);   // fly under K-loop

        f32x4 acc[4][4];
#pragma unroll
        for (int nf = 0; nf < 4; ++nf)
#pragma unroll
            for (int mf = 0; mf < 4; ++mf) acc[nf][mf] = (f32x4){0.f, 0.f, 0.f, 0.f};

        const float* S = Wbuf[cur];
        // ---- K-loop: 8 steps, no barriers; W frags from LDS (cvt), X frags from L1 ----
#pragma unroll
        for (int tt = 0; tt < 8; ++tt) {
            f16x8 xf[4];
#pragma unroll
            for (int mf = 0; mf < 4; ++mf)
                xf[mf] = *(const f16x8*)(xbase + mf * 16 * NH + tt * 32);
#pragma unroll
            for (int nf = 0; nf < 4; ++nf) {
                const int rl = nf * 16 + lr;                       // W-panel row 0..63
                const int c0 = tt * 8 + ((lg * 2)     ^ (rl & 7)); // undo swizzle
                const int c1 = tt * 8 + ((lg * 2 + 1) ^ (rl & 7));
                const f32x4 u0 = *(const f32x4*)(S + rl * 256 + c0 * 4);
                const f32x4 u1 = *(const f32x4*)(S + rl * 256 + c1 * 4);
                f16x8 h;
                h[0] = (_Float16)u0[0]; h[1] = (_Float16)u0[1];
                h[2] = (_Float16)u0[2]; h[3] = (_Float16)u0[3];
                h[4] = (_Float16)u1[0]; h[5] = (_Float16)u1[1];
                h[6] = (_Float16)u1[2]; h[7] = (_Float16)u1[3];
#pragma unroll
                for (int mf = 0; mf < 4; ++mf)
                    acc[nf][mf] = __builtin_amdgcn_mfma_f32_16x16x32_f16(
                        h, xf[mf], acc[nf][mf], 0, 0, 0);
            }
        }

        __syncthreads();   // all K reads of Wbuf[cur] done; t+1 loads (buf^1) drained

        // ---- epilogue: 2 passes x 256 rows via freed Wbuf[cur]; 256B-contig stores ----
        float* Cs = Wbuf[cur];                  // (256 rows x 64 cols) fp32
#pragma unroll
        for (int p2 = 0; p2 < 2; ++p2) {
            if ((w >> 2) == p2) {
                const int mloc = (w & 3) * 64;
#pragma unroll
                for (int nf = 0; nf < 4; ++nf) {
                    const int gn = n0 + nf * 16 + lg * 4;
                    const float4 bb = (gn < NI) ? *(const float4*)(bout + gn)
                                                : make_float4(0.f, 0.f, 0.f, 0.f);
#pragma unroll
                    for (int mf = 0; mf < 4; ++mf) {
                        const int mr = mloc + mf * 16 + lr;       // 0..255
                        const int ps = (nf * 4 + lg) ^ (lr & 7);  // swizzled float4 slot
                        float4 v;
                        v.x = tanh_fast(acc[nf][mf][0] + bb.x);
                        v.y = tanh_fast(acc[nf][mf][1] + bb.y);
                        v.z = tanh_fast(acc[nf][mf][2] + bb.z);
                        v.w = tanh_fast(acc[nf][mf][3] + bb.w);
                        *(float4*)(Cs + mr * 64 + ps * 4) = v;
                    }
                }
            }
            __syncthreads();
#pragma unroll
            for (int it = 0; it < 8; ++it) {
                const int fid = it * 512 + tid;    // 0..4095
                const int row = fid >> 4;          // 0..255
                const int c   = fid & 15;          // logical float4 chunk
                const int pq  = c ^ (row & 7);
                const int gn  = n0 + c * 4;
                if (gn < NI) {
                    const f32x4 v = *(const f32x4*)(Cs + row * 64 + pq * 4);
                    *(f32x4*)(C + (size_t)(p2 * 256 + row) * NI + gn) = v;
                }
            }
            __syncthreads();                       // Cs reads done -> writable again
        }
        cur ^= 1;
    }
}

extern "C" void kernel_launch(void* const* d_in, const int* in_sizes, int n_in,
                              void* d_out, int out_size, void* d_ws, size_t ws_size,
                              hipStream_t stream)
{
    const int*   idx    = (const int*)  d_in[0];
    const float* hidden = (const float*)d_in[1];   // (3,512,256)
    const float* Wih0   = (const float*)d_in[2];   // (768,100000)
    const float* WihHi  = (const float*)d_in[3];   // (2,768,256)
    const float* Whh    = (const float*)d_in[4];   // (3,768,256)
    const float* bih    = (const float*)d_in[5];   // (3,768)
    const float* bhh    = (const float*)d_in[6];   // (3,768)
    const float* Wout   = (const float*)d_in[7];   // (100000,256)
    const float* bout   = (const float*)d_in[8];   // (100000)

    float* act  = (float*)d_out;                  // (512, NI)
    float* hnew = act + (size_t)NB * NI;          // (3,512,256)
    // fp32 scratch lives in the activation region; final GEMM overwrites it.
    float* hp = act;                              // (3,512,768)
    float* xp = act + 3 * NB * H3;                // (512,768)
    // fp16 X lives in d_ws (must survive while the big GEMM writes act)
    _Float16* Xh = (_Float16*)d_ws;               // (512,256) = 256 KB

    const dim3 bs(256);
    const dim3 gs_hp(NB / 64, H3 / 64, 3);
    const dim3 gs_xp(NB / 64, H3 / 64, 1);

    // ---- all hidden-projections (depend only on input `hidden`) ----
    k_gemm_small<<<gs_hp, bs, 0, stream>>>(hidden, Whh, bhh, hp,
                                           NB, H3, NH, NB * NH, H3 * NH, H3, NB * H3);
    // ---- layer 0 (x_proj gathered inline) ----
    k_gates0<<<NB, bs, 0, stream>>>(idx, Wih0, bih, hp, hidden, hnew);
    // ---- layer 1 ----
    k_gemm_small<<<gs_xp, bs, 0, stream>>>(hnew, WihHi, bih + H3, xp,
                                           NB, H3, NH, 0, 0, 0, 0);
    k_gates<<<NB, bs, 0, stream>>>(xp, hp + NB * H3, hidden + NB * NH, hnew + NB * NH);
    // ---- layer 2 (also emits fp16 h2) ----
    k_gemm_small<<<gs_xp, bs, 0, stream>>>(hnew + NB * NH, WihHi + H3 * NH, bih + 2 * H3, xp,
                                           NB, H3, NH, 0, 0, 0, 0);
    k_gates_last<<<NB, bs, 0, stream>>>(xp, hp + 2 * NB * H3, hidden + 2 * NB * NH,
                                        hnew + 2 * NB * NH, Xh);

    // ---- output projection: 256 pipelined blocks (1/CU) x ~6 tiles each ----
    k_out_mfma<<<dim3(GRID_OUT), dim3(512), 0, stream>>>(Xh, Wout, bout, act);
}

// Round 14
// 204.762 us; speedup vs baseline: 1.7565x; 1.0823x over previous
//
#include <hip/hip_runtime.h>
#include <math.h>
#include <stdint.h>

#define NI 100000   // N_ITEMS
#define NB 512      // batch
#define NH 256      // hidden H
#define H3 768      // 3*H

typedef _Float16 f16x8 __attribute__((ext_vector_type(8)));
typedef float    f32x4 __attribute__((ext_vector_type(4)));

__device__ __forceinline__ float tanh_fast(float x) {
    x = fminf(fmaxf(x, -9.0f), 9.0f);
    const float e = __expf(2.0f * x);
    return (e - 1.0f) * __builtin_amdgcn_rcpf(e + 1.0f);
}

// ---------------- GRU gate elementwise (layer 0: gather x_proj inline) ----------------
__global__ void k_gates0(const int* __restrict__ idx,
                         const float* __restrict__ Wih0,   // (768, NI)
                         const float* __restrict__ bih0,   // (768)
                         const float* __restrict__ hp,     // (512,768)
                         const float* __restrict__ hprev,  // (512,256)
                         float* __restrict__ hnew)         // (512,256)
{
    const int b = blockIdx.x;
    const int j = threadIdx.x;          // 0..255
    const int ib = idx[b];
    const float xr = Wih0[(size_t)(j          ) * NI + ib] + bih0[j];
    const float xz = Wih0[(size_t)(j + NH     ) * NI + ib] + bih0[j + NH];
    const float xn = Wih0[(size_t)(j + 2 * NH ) * NI + ib] + bih0[j + 2 * NH];
    const float hr = hp[b * H3 + j];
    const float hz = hp[b * H3 + NH + j];
    const float hn = hp[b * H3 + 2 * NH + j];
    const float h  = hprev[b * NH + j];
    const float r = 1.0f / (1.0f + expf(-(xr + hr)));
    const float z = 1.0f / (1.0f + expf(-(xz + hz)));
    const float n = tanhf(xn + r * hn);
    hnew[b * NH + j] = (1.0f - z) * n + z * h;
}

// ---------------- GRU gate elementwise (layer 1) ----------------
__global__ void k_gates(const float* __restrict__ xp,
                        const float* __restrict__ hp,
                        const float* __restrict__ hprev,
                        float* __restrict__ hnew)
{
    const int b = blockIdx.x;
    const int j = threadIdx.x;
    const float xr = xp[b * H3 + j];
    const float xz = xp[b * H3 + NH + j];
    const float xn = xp[b * H3 + 2 * NH + j];
    const float hr = hp[b * H3 + j];
    const float hz = hp[b * H3 + NH + j];
    const float hn = hp[b * H3 + 2 * NH + j];
    const float h  = hprev[b * NH + j];
    const float r = 1.0f / (1.0f + expf(-(xr + hr)));
    const float z = 1.0f / (1.0f + expf(-(xz + hz)));
    const float n = tanhf(xn + r * hn);
    hnew[b * NH + j] = (1.0f - z) * n + z * h;
}

// ---------------- layer 2 gates: also emit fp16 copy of h2 for the MFMA GEMM --------
__global__ void k_gates_last(const float* __restrict__ xp,
                             const float* __restrict__ hp,
                             const float* __restrict__ hprev,
                             float* __restrict__ hnew,
                             _Float16* __restrict__ Xh)    // (512,256) fp16
{
    const int b = blockIdx.x;
    const int j = threadIdx.x;
    const float xr = xp[b * H3 + j];
    const float xz = xp[b * H3 + NH + j];
    const float xn = xp[b * H3 + 2 * NH + j];
    const float hr = hp[b * H3 + j];
    const float hz = hp[b * H3 + NH + j];
    const float hn = hp[b * H3 + 2 * NH + j];
    const float h  = hprev[b * NH + j];
    const float r = 1.0f / (1.0f + expf(-(xr + hr)));
    const float z = 1.0f / (1.0f + expf(-(xz + hz)));
    const float n = tanhf(xn + r * hn);
    const float v = (1.0f - z) * n + z * h;
    hnew[b * NH + j] = v;
    Xh[b * NH + j] = (_Float16)v;
}

// ---------------- small tiled fp32 GEMM:  C = A @ B.T + bias (z-batched) ----------------
__global__ __launch_bounds__(256)
void k_gemm_small(const float* __restrict__ A0,
                  const float* __restrict__ B0,
                  const float* __restrict__ bias0,
                  float* __restrict__ C0,
                  int M, int N, int K,
                  int sA, int sB, int sBias, int sC)
{
    constexpr int BM = 64, BN = 64, BK = 32;
    __shared__ float As[BK][BM];
    __shared__ float Bs[BK][BN];

    const float* A    = A0 + (size_t)blockIdx.z * sA;
    const float* Bm   = B0 + (size_t)blockIdx.z * sB;
    const float* bias = bias0 + (size_t)blockIdx.z * sBias;
    float*       C    = C0 + (size_t)blockIdx.z * sC;

    const int tid = threadIdx.x;
    const int tx  = tid & 15;
    const int ty  = tid >> 4;
    const int m0  = blockIdx.x * BM;
    const int n0  = blockIdx.y * BN;

    float acc[4][4];
#pragma unroll
    for (int i = 0; i < 4; i++)
#pragma unroll
        for (int j = 0; j < 4; j++) acc[i][j] = 0.0f;

    for (int k0 = 0; k0 < K; k0 += BK) {
#pragma unroll
        for (int f = 0; f < 2; f++) {
            const int fid = tid + f * 256;
            const int row = fid >> 3;
            const int t4  = fid & 7;
            const int mp  = row ^ ((t4 & 3) << 3);
            {
                const float4 v = *(const float4*)(A + (size_t)(m0 + row) * K + k0 + t4 * 4);
                As[t4 * 4 + 0][mp] = v.x; As[t4 * 4 + 1][mp] = v.y;
                As[t4 * 4 + 2][mp] = v.z; As[t4 * 4 + 3][mp] = v.w;
            }
            {
                const float4 v = *(const float4*)(Bm + (size_t)(n0 + row) * K + k0 + t4 * 4);
                Bs[t4 * 4 + 0][mp] = v.x; Bs[t4 * 4 + 1][mp] = v.y;
                Bs[t4 * 4 + 2][mp] = v.z; Bs[t4 * 4 + 3][mp] = v.w;
            }
        }
        __syncthreads();
#pragma unroll
        for (int kk = 0; kk < BK; kk++) {
            const int s = ((kk >> 2) & 3) << 3;
            const float4 a0 = *(const float4*)&As[kk][(ty * 4) ^ s];
            const float4 b0 = *(const float4*)&Bs[kk][(tx * 4) ^ s];
            const float av[4] = {a0.x, a0.y, a0.z, a0.w};
            const float bv[4] = {b0.x, b0.y, b0.z, b0.w};
#pragma unroll
            for (int i = 0; i < 4; i++)
#pragma unroll
                for (int j = 0; j < 4; j++)
                    acc[i][j] = fmaf(av[i], bv[j], acc[i][j]);
        }
        __syncthreads();
    }

#pragma unroll
    for (int i = 0; i < 4; i++) {
        const size_t rowoff = (size_t)(m0 + ty * 4 + i) * N;
        const int gn = n0 + tx * 4;
        const float4 bb = *(const float4*)(bias + gn);
        float4 v;
        v.x = acc[i][0] + bb.x; v.y = acc[i][1] + bb.y;
        v.z = acc[i][2] + bb.z; v.w = acc[i][3] + bb.w;
        *(float4*)(C + rowoff + gn) = v;
    }
}

// ---------------- output projection: act = tanh(x @ Wout.T + bout), fp16 MFMA ----------
// R14 = the Round-7 kernel (best out-GEMM so far, ~130us) with ONE change:
// launch_bounds (512,4) -> (512,2). Empirical allocator law (R8/R9/R10/R12):
// VGPR cap = 256/minWaves -> (512,4) capped this kernel at 64 regs (acc alone is 64)
// => it was SPILLING while still fastest. (512,2) caps at 128 (need ~110: acc 64 +
// xf 16 + cvt/addr temps ~30) => no spill, and 2 blocks/CU still fit
// (2 x 8 waves x <=128 regs = 2048/CU, 2 x 64KB LDS = 128KB). Everything else
// byte-identical to the verified Round-7 kernel (absmax 4.88e-4).
// Structure: BM=512 (whole batch), BN=64/block -> W fetched exactly once; full K=256
// W panel staged fp32 via global_load_lds (1KB rows, src-side 16B-chunk XOR swizzle);
// K-loop barrier-free (cvt fp32->fp16 on LDS read); epilogue = 2 passes x 256 rows
// through the freed buffer -> 256B-contiguous C stores.
// mfma(A=W, B=X): D row((lane>>4)*4+reg)=n, col(lane&15)=m (verified r1-r13).
__global__ __launch_bounds__(512, 2)
void k_out_mfma(const _Float16* __restrict__ Xh,  // (512,256) fp16
                const float* __restrict__ W,      // (NI,256) fp32
                const float* __restrict__ bout,   // (NI)
                float* __restrict__ C)            // (512,NI)
{
    __shared__ __align__(16) float S[16384];   // 64 KB: W panel, then C half-tiles

    const int n0   = blockIdx.x * 64;          // n-tile base (1563 tiles)
    const int tid  = threadIdx.x;
    const int w    = tid >> 6;                 // wave 0..7 -> m rows [w*64, w*64+64)
    const int lane = tid & 63;
    const int lr   = lane & 15;
    const int lg   = lane >> 4;                // 0..3

    // ---- stage W panel: 64 rows x 64 16B-chunks; each wave-instr = one full 1KB row ----
#pragma unroll
    for (int it = 0; it < 8; ++it) {
        const int fid = it * 512 + tid;        // chunk id 0..4095
        const int row = fid >> 6;              // 0..63
        const int p   = fid & 63;              // physical chunk in LDS row
        int gr = n0 + row; if (gr >= NI) gr = NI - 1;      // clamp; cols masked later
        const float* src = W + (size_t)gr * NH + (size_t)(p ^ (row & 7)) * 4;
        __builtin_amdgcn_global_load_lds(
            (const __attribute__((address_space(1))) void*)src,
            (__attribute__((address_space(3))) void*)(S + fid * 4),
            16, 0, 0);
    }

    f32x4 acc[4][4];
#pragma unroll
    for (int nf = 0; nf < 4; ++nf)
#pragma unroll
        for (int mf = 0; mf < 4; ++mf) acc[nf][mf] = (f32x4){0.f, 0.f, 0.f, 0.f};

    __syncthreads();

    const _Float16* xbase = Xh + (size_t)(w * 64 + lr) * NH + lg * 8;

    // ---- K-loop: 8 steps, no barriers; W frags from LDS (cvt), X frags from L2 ----
#pragma unroll
    for (int t = 0; t < 8; ++t) {
        f16x8 xf[4];
#pragma unroll
        for (int mf = 0; mf < 4; ++mf)
            xf[mf] = *(const f16x8*)(xbase + mf * 16 * NH + t * 32);
#pragma unroll
        for (int nf = 0; nf < 4; ++nf) {
            const int rl = nf * 16 + lr;                      // W-panel row 0..63
            const int c0 = t * 8 + ((lg * 2)     ^ (rl & 7)); // phys chunk (undo swizzle)
            const int c1 = t * 8 + ((lg * 2 + 1) ^ (rl & 7));
            const f32x4 u0 = *(const f32x4*)(S + rl * 256 + c0 * 4);
            const f32x4 u1 = *(const f32x4*)(S + rl * 256 + c1 * 4);
            f16x8 h;
            h[0] = (_Float16)u0[0]; h[1] = (_Float16)u0[1];
            h[2] = (_Float16)u0[2]; h[3] = (_Float16)u0[3];
            h[4] = (_Float16)u1[0]; h[5] = (_Float16)u1[1];
            h[6] = (_Float16)u1[2]; h[7] = (_Float16)u1[3];
#pragma unroll
            for (int mf = 0; mf < 4; ++mf)
                acc[nf][mf] = __builtin_amdgcn_mfma_f32_16x16x32_f16(
                    h, xf[mf], acc[nf][mf], 0, 0, 0);
        }
    }

    // ---- epilogue: 2 passes (256 rows each) via LDS; 256B-contiguous global stores ----
#pragma unroll
    for (int pass = 0; pass < 2; ++pass) {
        __syncthreads();                       // pass 0: all k-loop LDS reads done
        if ((w >> 2) == pass) {
            const int mloc = (w & 3) * 64;
#pragma unroll
            for (int nf = 0; nf < 4; ++nf) {
                const int gn = n0 + nf * 16 + lg * 4;
                const float4 bb = (gn < NI) ? *(const float4*)(bout + gn)
                                            : make_float4(0.f, 0.f, 0.f, 0.f);
#pragma unroll
                for (int mf = 0; mf < 4; ++mf) {
                    const int mr = mloc + mf * 16 + lr;       // 0..255
                    const int p  = (nf * 4 + lg) ^ (lr & 7);  // swizzled float4 slot
                    float4 v;
                    v.x = tanh_fast(acc[nf][mf][0] + bb.x);
                    v.y = tanh_fast(acc[nf][mf][1] + bb.y);
                    v.z = tanh_fast(acc[nf][mf][2] + bb.z);
                    v.w = tanh_fast(acc[nf][mf][3] + bb.w);
                    *(float4*)(S + mr * 64 + p * 4) = v;
                }
            }
        }
        __syncthreads();
#pragma unroll
        for (int it = 0; it < 8; ++it) {
            const int fid = it * 512 + tid;    // 0..4095
            const int row = fid >> 4;          // 0..255
            const int c   = fid & 15;          // logical float4 chunk
            const int gn  = n0 + c * 4;
            if (gn < NI) {
                const f32x4 v = *(const f32x4*)(S + row * 64 + ((c ^ (row & 7)) * 4));
                *(f32x4*)(C + (size_t)(pass * 256 + row) * NI + gn) = v;
            }
        }
    }
}

extern "C" void kernel_launch(void* const* d_in, const int* in_sizes, int n_in,
                              void* d_out, int out_size, void* d_ws, size_t ws_size,
                              hipStream_t stream)
{
    const int*   idx    = (const int*)  d_in[0];
    const float* hidden = (const float*)d_in[1];   // (3,512,256)
    const float* Wih0   = (const float*)d_in[2];   // (768,100000)
    const float* WihHi  = (const float*)d_in[3];   // (2,768,256)
    const float* Whh    = (const float*)d_in[4];   // (3,768,256)
    const float* bih    = (const float*)d_in[5];   // (3,768)
    const float* bhh    = (const float*)d_in[6];   // (3,768)
    const float* Wout   = (const float*)d_in[7];   // (100000,256)
    const float* bout   = (const float*)d_in[8];   // (100000)

    float* act  = (float*)d_out;                  // (512, NI)
    float* hnew = act + (size_t)NB * NI;          // (3,512,256)
    // fp32 scratch lives in the activation region; final GEMM overwrites it.
    float* hp = act;                              // (3,512,768)
    float* xp = act + 3 * NB * H3;                // (512,768)
    // fp16 X lives in d_ws (must survive while the big GEMM writes act)
    _Float16* Xh = (_Float16*)d_ws;               // (512,256) = 256 KB

    const dim3 bs(256);
    const dim3 gs_hp(NB / 64, H3 / 64, 3);
    const dim3 gs_xp(NB / 64, H3 / 64, 1);

    // ---- all hidden-projections (depend only on input `hidden`) ----
    k_gemm_small<<<gs_hp, bs, 0, stream>>>(hidden, Whh, bhh, hp,
                                           NB, H3, NH, NB * NH, H3 * NH, H3, NB * H3);
    // ---- layer 0 (x_proj gathered inline) ----
    k_gates0<<<NB, bs, 0, stream>>>(idx, Wih0, bih, hp, hidden, hnew);
    // ---- layer 1 ----
    k_gemm_small<<<gs_xp, bs, 0, stream>>>(hnew, WihHi, bih + H3, xp,
                                           NB, H3, NH, 0, 0, 0, 0);
    k_gates<<<NB, bs, 0, stream>>>(xp, hp + NB * H3, hidden + NB * NH, hnew + NB * NH);
    // ---- layer 2 (also emits fp16 h2) ----
    k_gemm_small<<<gs_xp, bs, 0, stream>>>(hnew + NB * NH, WihHi + H3 * NH, bih + 2 * H3, xp,
                                           NB, H3, NH, 0, 0, 0, 0);
    k_gates_last<<<NB, bs, 0, stream>>>(xp, hp + 2 * NB * H3, hidden + 2 * NB * NH,
                                        hnew + 2 * NB * NH, Xh);

    // ---- output projection: 1563 n-tiles of 64, whole batch per block ----
    k_out_mfma<<<dim3((NI + 63) / 64), dim3(512), 0, stream>>>(Xh, Wout, bout, act);
}

// Round 15
// 148.271 us; speedup vs baseline: 2.4257x; 1.3810x over previous
//
#include <hip/hip_runtime.h>
#include <math.h>
#include <stdint.h>

#define NI 100000   // N_ITEMS
#define NB 512      // batch
#define NH 256      // hidden H
#define H3 768      // 3*H

typedef _Float16 f16x8 __attribute__((ext_vector_type(8)));
typedef float    f32x4 __attribute__((ext_vector_type(4)));

__device__ __forceinline__ float tanh_fast(float x) {
    x = fminf(fmaxf(x, -9.0f), 9.0f);
    const float e = __expf(2.0f * x);
    return (e - 1.0f) * __builtin_amdgcn_rcpf(e + 1.0f);
}

// ---------------- GRU gate elementwise (layer 0: gather x_proj inline) ----------------
__global__ void k_gates0(const int* __restrict__ idx,
                         const float* __restrict__ Wih0,   // (768, NI)
                         const float* __restrict__ bih0,   // (768)
                         const float* __restrict__ hp,     // (512,768)
                         const float* __restrict__ hprev,  // (512,256)
                         float* __restrict__ hnew)         // (512,256)
{
    const int b = blockIdx.x;
    const int j = threadIdx.x;          // 0..255
    const int ib = idx[b];
    const float xr = Wih0[(size_t)(j          ) * NI + ib] + bih0[j];
    const float xz = Wih0[(size_t)(j + NH     ) * NI + ib] + bih0[j + NH];
    const float xn = Wih0[(size_t)(j + 2 * NH ) * NI + ib] + bih0[j + 2 * NH];
    const float hr = hp[b * H3 + j];
    const float hz = hp[b * H3 + NH + j];
    const float hn = hp[b * H3 + 2 * NH + j];
    const float h  = hprev[b * NH + j];
    const float r = 1.0f / (1.0f + expf(-(xr + hr)));
    const float z = 1.0f / (1.0f + expf(-(xz + hz)));
    const float n = tanhf(xn + r * hn);
    hnew[b * NH + j] = (1.0f - z) * n + z * h;
}

// ---------------- GRU gate elementwise (layer 1) ----------------
__global__ void k_gates(const float* __restrict__ xp,
                        const float* __restrict__ hp,
                        const float* __restrict__ hprev,
                        float* __restrict__ hnew)
{
    const int b = blockIdx.x;
    const int j = threadIdx.x;
    const float xr = xp[b * H3 + j];
    const float xz = xp[b * H3 + NH + j];
    const float xn = xp[b * H3 + 2 * NH + j];
    const float hr = hp[b * H3 + j];
    const float hz = hp[b * H3 + NH + j];
    const float hn = hp[b * H3 + 2 * NH + j];
    const float h  = hprev[b * NH + j];
    const float r = 1.0f / (1.0f + expf(-(xr + hr)));
    const float z = 1.0f / (1.0f + expf(-(xz + hz)));
    const float n = tanhf(xn + r * hn);
    hnew[b * NH + j] = (1.0f - z) * n + z * h;
}

// ---------------- layer 2 gates: also emit fp16 copy of h2 for the MFMA GEMM --------
__global__ void k_gates_last(const float* __restrict__ xp,
                             const float* __restrict__ hp,
                             const float* __restrict__ hprev,
                             float* __restrict__ hnew,
                             _Float16* __restrict__ Xh)    // (512,256) fp16
{
    const int b = blockIdx.x;
    const int j = threadIdx.x;
    const float xr = xp[b * H3 + j];
    const float xz = xp[b * H3 + NH + j];
    const float xn = xp[b * H3 + 2 * NH + j];
    const float hr = hp[b * H3 + j];
    const float hz = hp[b * H3 + NH + j];
    const float hn = hp[b * H3 + 2 * NH + j];
    const float h  = hprev[b * NH + j];
    const float r = 1.0f / (1.0f + expf(-(xr + hr)));
    const float z = 1.0f / (1.0f + expf(-(xz + hz)));
    const float n = tanhf(xn + r * hn);
    const float v = (1.0f - z) * n + z * h;
    hnew[b * NH + j] = v;
    Xh[b * NH + j] = (_Float16)v;
}

// ---------------- small tiled fp32 GEMM:  C = A @ B.T + bias (z-batched) ----------------
// BK=64 (was 32): halves barrier count (8 per k-loop vs 16) for these latency-bound
// small GEMMs. LDS 2 x 16KB = 32KB.
__global__ __launch_bounds__(256)
void k_gemm_small(const float* __restrict__ A0,
                  const float* __restrict__ B0,
                  const float* __restrict__ bias0,
                  float* __restrict__ C0,
                  int M, int N, int K,
                  int sA, int sB, int sBias, int sC)
{
    constexpr int BM = 64, BN = 64, BK = 64;
    __shared__ float As[BK][BM];
    __shared__ float Bs[BK][BN];

    const float* A    = A0 + (size_t)blockIdx.z * sA;
    const float* Bm   = B0 + (size_t)blockIdx.z * sB;
    const float* bias = bias0 + (size_t)blockIdx.z * sBias;
    float*       C    = C0 + (size_t)blockIdx.z * sC;

    const int tid = threadIdx.x;
    const int tx  = tid & 15;
    const int ty  = tid >> 4;
    const int m0  = blockIdx.x * BM;
    const int n0  = blockIdx.y * BN;

    float acc[4][4];
#pragma unroll
    for (int i = 0; i < 4; i++)
#pragma unroll
        for (int j = 0; j < 4; j++) acc[i][j] = 0.0f;

    for (int k0 = 0; k0 < K; k0 += BK) {
#pragma unroll
        for (int f = 0; f < 4; f++) {
            const int fid = tid + f * 256;       // 0..1023
            const int row = fid >> 4;            // 0..63
            const int t4  = fid & 15;            // 16 float4 per 64-k row
            const int mp  = row ^ ((t4 & 3) << 3);
            {
                const float4 v = *(const float4*)(A + (size_t)(m0 + row) * K + k0 + t4 * 4);
                As[t4 * 4 + 0][mp] = v.x; As[t4 * 4 + 1][mp] = v.y;
                As[t4 * 4 + 2][mp] = v.z; As[t4 * 4 + 3][mp] = v.w;
            }
            {
                const float4 v = *(const float4*)(Bm + (size_t)(n0 + row) * K + k0 + t4 * 4);
                Bs[t4 * 4 + 0][mp] = v.x; Bs[t4 * 4 + 1][mp] = v.y;
                Bs[t4 * 4 + 2][mp] = v.z; Bs[t4 * 4 + 3][mp] = v.w;
            }
        }
        __syncthreads();
#pragma unroll
        for (int kk = 0; kk < BK; kk++) {
            const int s = ((kk >> 2) & 3) << 3;
            const float4 a0 = *(const float4*)&As[kk][(ty * 4) ^ s];
            const float4 b0 = *(const float4*)&Bs[kk][(tx * 4) ^ s];
            const float av[4] = {a0.x, a0.y, a0.z, a0.w};
            const float bv[4] = {b0.x, b0.y, b0.z, b0.w};
#pragma unroll
            for (int i = 0; i < 4; i++)
#pragma unroll
                for (int j = 0; j < 4; j++)
                    acc[i][j] = fmaf(av[i], bv[j], acc[i][j]);
        }
        __syncthreads();
    }

#pragma unroll
    for (int i = 0; i < 4; i++) {
        const size_t rowoff = (size_t)(m0 + ty * 4 + i) * N;
        const int gn = n0 + tx * 4;
        const float4 bb = *(const float4*)(bias + gn);
        float4 v;
        v.x = acc[i][0] + bb.x; v.y = acc[i][1] + bb.y;
        v.z = acc[i][2] + bb.z; v.w = acc[i][3] + bb.w;
        *(float4*)(C + rowoff + gn) = v;
    }
}

// ---------------- output projection: act = tanh(x @ Wout.T + bout), fp16 MFMA ----------
// EXACT restore of the Round-7 kernel (best measured: total 180.9us, out ~130us) with
// one addition: NONTEMPORAL C stores (C is write-once; bypass L2 so the 205MB write
// stream doesn't evict W/X lines).
// ALLOCATOR MODEL (R7..R14 synthesis): launch_bounds caps ARCH VGPRs at ~256/minW;
// the MFMA acc lives in AGPRs ON TOP. (512,4): 64 arch + 64 agpr = 128/wave ->
// 16 waves/CU = 2 blocks resident, NO spill (acc in AGPR). (512,2) let arch grow ->
// 192/wave -> 1 block/CU -> R14 regression. (512,4) is this structure's optimum.
// Structure: BM=512 (whole batch), BN=64/block -> W fetched exactly once; full K=256
// W panel (64KB fp32) staged via global_load_lds (1KB rows, src-side 16B-chunk XOR
// swizzle); K-loop barrier-free (cvt fp32->fp16 on LDS read); epilogue = 2 passes
// x 256 rows through the freed buffer -> 256B-contiguous C stores.
// mfma(A=W, B=X): D row((lane>>4)*4+reg)=n, col(lane&15)=m (verified r1-r14).
__global__ __launch_bounds__(512, 4)
void k_out_mfma(const _Float16* __restrict__ Xh,  // (512,256) fp16
                const float* __restrict__ W,      // (NI,256) fp32
                const float* __restrict__ bout,   // (NI)
                float* __restrict__ C)            // (512,NI)
{
    __shared__ __align__(16) float S[16384];   // 64 KB: W panel, then C half-tiles

    const int n0   = blockIdx.x * 64;          // n-tile base (1563 tiles)
    const int tid  = threadIdx.x;
    const int w    = tid >> 6;                 // wave 0..7 -> m rows [w*64, w*64+64)
    const int lane = tid & 63;
    const int lr   = lane & 15;
    const int lg   = lane >> 4;                // 0..3

    // ---- stage W panel: 64 rows x 64 16B-chunks; each wave-instr = one full 1KB row ----
#pragma unroll
    for (int it = 0; it < 8; ++it) {
        const int fid = it * 512 + tid;        // chunk id 0..4095
        const int row = fid >> 6;              // 0..63
        const int p   = fid & 63;              // physical chunk in LDS row
        int gr = n0 + row; if (gr >= NI) gr = NI - 1;      // clamp; cols masked later
        const float* src = W + (size_t)gr * NH + (size_t)(p ^ (row & 7)) * 4;
        __builtin_amdgcn_global_load_lds(
            (const __attribute__((address_space(1))) void*)src,
            (__attribute__((address_space(3))) void*)(S + fid * 4),
            16, 0, 0);
    }

    f32x4 acc[4][4];
#pragma unroll
    for (int nf = 0; nf < 4; ++nf)
#pragma unroll
        for (int mf = 0; mf < 4; ++mf) acc[nf][mf] = (f32x4){0.f, 0.f, 0.f, 0.f};

    __syncthreads();

    const _Float16* xbase = Xh + (size_t)(w * 64 + lr) * NH + lg * 8;

    // ---- K-loop: 8 steps, no barriers; W frags from LDS (cvt), X frags from L2 ----
#pragma unroll
    for (int t = 0; t < 8; ++t) {
        f16x8 xf[4];
#pragma unroll
        for (int mf = 0; mf < 4; ++mf)
            xf[mf] = *(const f16x8*)(xbase + mf * 16 * NH + t * 32);
#pragma unroll
        for (int nf = 0; nf < 4; ++nf) {
            const int rl = nf * 16 + lr;                      // W-panel row 0..63
            const int c0 = t * 8 + ((lg * 2)     ^ (rl & 7)); // phys chunk (undo swizzle)
            const int c1 = t * 8 + ((lg * 2 + 1) ^ (rl & 7));
            const f32x4 u0 = *(const f32x4*)(S + rl * 256 + c0 * 4);
            const f32x4 u1 = *(const f32x4*)(S + rl * 256 + c1 * 4);
            f16x8 h;
            h[0] = (_Float16)u0[0]; h[1] = (_Float16)u0[1];
            h[2] = (_Float16)u0[2]; h[3] = (_Float16)u0[3];
            h[4] = (_Float16)u1[0]; h[5] = (_Float16)u1[1];
            h[6] = (_Float16)u1[2]; h[7] = (_Float16)u1[3];
#pragma unroll
            for (int mf = 0; mf < 4; ++mf)
                acc[nf][mf] = __builtin_amdgcn_mfma_f32_16x16x32_f16(
                    h, xf[mf], acc[nf][mf], 0, 0, 0);
        }
    }

    // ---- epilogue: 2 passes (256 rows each) via LDS; 256B-contiguous NT stores ----
#pragma unroll
    for (int pass = 0; pass < 2; ++pass) {
        __syncthreads();                       // pass 0: all k-loop LDS reads done
        if ((w >> 2) == pass) {
            const int mloc = (w & 3) * 64;
#pragma unroll
            for (int nf = 0; nf < 4; ++nf) {
                const int gn = n0 + nf * 16 + lg * 4;
                const float4 bb = (gn < NI) ? *(const float4*)(bout + gn)
                                            : make_float4(0.f, 0.f, 0.f, 0.f);
#pragma unroll
                for (int mf = 0; mf < 4; ++mf) {
                    const int mr = mloc + mf * 16 + lr;       // 0..255
                    const int p  = (nf * 4 + lg) ^ (lr & 7);  // swizzled float4 slot
                    float4 v;
                    v.x = tanh_fast(acc[nf][mf][0] + bb.x);
                    v.y = tanh_fast(acc[nf][mf][1] + bb.y);
                    v.z = tanh_fast(acc[nf][mf][2] + bb.z);
                    v.w = tanh_fast(acc[nf][mf][3] + bb.w);
                    *(float4*)(S + mr * 64 + p * 4) = v;
                }
            }
        }
        __syncthreads();
#pragma unroll
        for (int it = 0; it < 8; ++it) {
            const int fid = it * 512 + tid;    // 0..4095
            const int row = fid >> 4;          // 0..255
            const int c   = fid & 15;          // logical float4 chunk
            const int gn  = n0 + c * 4;
            if (gn < NI) {
                const f32x4 v = *(const f32x4*)(S + row * 64 + ((c ^ (row & 7)) * 4));
                __builtin_nontemporal_store(
                    v, (f32x4*)(C + (size_t)(pass * 256 + row) * NI + gn));
            }
        }
    }
}

extern "C" void kernel_launch(void* const* d_in, const int* in_sizes, int n_in,
                              void* d_out, int out_size, void* d_ws, size_t ws_size,
                              hipStream_t stream)
{
    const int*   idx    = (const int*)  d_in[0];
    const float* hidden = (const float*)d_in[1];   // (3,512,256)
    const float* Wih0   = (const float*)d_in[2];   // (768,100000)
    const float* WihHi  = (const float*)d_in[3];   // (2,768,256)
    const float* Whh    = (const float*)d_in[4];   // (3,768,256)
    const float* bih    = (const float*)d_in[5];   // (3,768)
    const float* bhh    = (const float*)d_in[6];   // (3,768)
    const float* Wout   = (const float*)d_in[7];   // (100000,256)
    const float* bout   = (const float*)d_in[8];   // (100000)

    float* act  = (float*)d_out;                  // (512, NI)
    float* hnew = act + (size_t)NB * NI;          // (3,512,256)
    // fp32 scratch lives in the activation region; final GEMM overwrites it.
    float* hp = act;                              // (3,512,768)
    float* xp = act + 3 * NB * H3;                // (512,768)
    // fp16 X lives in d_ws (must survive while the big GEMM writes act)
    _Float16* Xh = (_Float16*)d_ws;               // (512,256) = 256 KB

    const dim3 bs(256);
    const dim3 gs_hp(NB / 64, H3 / 64, 3);
    const dim3 gs_xp(NB / 64, H3 / 64, 1);

    // ---- all hidden-projections (depend only on input `hidden`) ----
    k_gemm_small<<<gs_hp, bs, 0, stream>>>(hidden, Whh, bhh, hp,
                                           NB, H3, NH, NB * NH, H3 * NH, H3, NB * H3);
    // ---- layer 0 (x_proj gathered inline) ----
    k_gates0<<<NB, bs, 0, stream>>>(idx, Wih0, bih, hp, hidden, hnew);
    // ---- layer 1 ----
    k_gemm_small<<<gs_xp, bs, 0, stream>>>(hnew, WihHi, bih + H3, xp,
                                           NB, H3, NH, 0, 0, 0, 0);
    k_gates<<<NB, bs, 0, stream>>>(xp, hp + NB * H3, hidden + NB * NH, hnew + NB * NH);
    // ---- layer 2 (also emits fp16 h2) ----
    k_gemm_small<<<gs_xp, bs, 0, stream>>>(hnew + NB * NH, WihHi + H3 * NH, bih + 2 * H3, xp,
                                           NB, H3, NH, 0, 0, 0, 0);
    k_gates_last<<<NB, bs, 0, stream>>>(xp, hp + 2 * NB * H3, hidden + 2 * NB * NH,
                                        hnew + 2 * NB * NH, Xh);

    // ---- output projection: 1563 n-tiles of 64, whole batch per block ----
    k_out_mfma<<<dim3((NI + 63) / 64), dim3(512), 0, stream>>>(Xh, Wout, bout, act);
}